// Round 14
// baseline (275.119 us; speedup 1.0000x reference)
//
#include <hip/hip_runtime.h>
#include <hip/hip_bf16.h>

#define B_ 64
#define L_ 512
#define H_ 1024
#define EPS_ 1e-13f

typedef unsigned short u16;
typedef __attribute__((ext_vector_type(8))) short s16x8;
typedef __attribute__((ext_vector_type(4))) float f32x4;

__device__ __forceinline__ u16 f2bf(float f) {
  __hip_bfloat16 h = __float2bfloat16(f);
  union { __hip_bfloat16 h; u16 u; } c; c.h = h; return c.u;
}

// ---- Kernel 1: row softmax + mask renorm -> W bf16 (proven, ~27 us at BW floor) ----
__global__ __launch_bounds__(256) void softmax_rows(const float* __restrict__ att,
                                                    const float* __restrict__ mask,
                                                    u16* __restrict__ Wout) {
  const int w = threadIdx.x >> 6, lane = threadIdx.x & 63;
  const int row0 = blockIdx.x * 16 + w * 4;

  float a[4][8];
#pragma unroll
  for (int r = 0; r < 4; ++r) {
    const float* p = att + (size_t)(row0 + r) * L_ + lane * 8;
    float4 v0 = *(const float4*)p;
    float4 v1 = *(const float4*)(p + 4);
    a[r][0] = v0.x; a[r][1] = v0.y; a[r][2] = v0.z; a[r][3] = v0.w;
    a[r][4] = v1.x; a[r][5] = v1.y; a[r][6] = v1.z; a[r][7] = v1.w;
  }

  float m[4];
#pragma unroll
  for (int r = 0; r < 4; ++r) {
    m[r] = a[r][0];
#pragma unroll
    for (int j = 1; j < 8; ++j) m[r] = fmaxf(m[r], a[r][j]);
  }
#pragma unroll
  for (int off = 32; off > 0; off >>= 1)
#pragma unroll
    for (int r = 0; r < 4; ++r) m[r] = fmaxf(m[r], __shfl_xor(m[r], off));

  float z[4] = {0.f, 0.f, 0.f, 0.f};
#pragma unroll
  for (int r = 0; r < 4; ++r)
#pragma unroll
    for (int j = 0; j < 8; ++j) { a[r][j] = __expf(a[r][j] - m[r]); z[r] += a[r][j]; }
#pragma unroll
  for (int off = 32; off > 0; off >>= 1)
#pragma unroll
    for (int r = 0; r < 4; ++r) z[r] += __shfl_xor(z[r], off);

#pragma unroll
  for (int r = 0; r < 4; ++r) {
    const float mk = mask[row0 + r];
    const float c = (1.0f / z[r]) * (mk / (mk + EPS_));  // softmax row-sum == 1
    union { u16 u[8]; uint4 v; } wv;
#pragma unroll
    for (int j = 0; j < 8; ++j) wv.u[j] = f2bf(a[r][j] * c);
    *(uint4*)(Wout + (size_t)(row0 + r) * L_ + lane * 8) = wv.v;
  }
}

#define GLOAD(gp, lp)                                                              \
  __builtin_amdgcn_global_load_lds((const __attribute__((address_space(1))) unsigned*)(gp), \
                                   (__attribute__((address_space(3))) unsigned*)(void*)(lp), 16, 0, 0)

// ---- Kernel 2: GEMM out = W @ X, tile M=64 x N=1024 (FULL H row).
// Every global stream contiguous: X k-rows = full 4KB lines (gload_lds,
// row-major f32 slab in LDS), out rows = full 4KB lines, W rows K-contig.
// N processed as two 512-halves per K-tile (B slab 64KB ring-2 + A 2x4KB).
// B-frags: 8x b32 column gather + cvt; granule-XOR pre-swizzle -> 2-way banks
// (free). 8 m-blocks of a batch share X slabs via one XCD's L2.
__global__ __launch_bounds__(512, 2) void gemm_fc(const u16* __restrict__ Wm,
                                                  const float* __restrict__ X,
                                                  float* __restrict__ out) {
  const int NT = 16;  // K=512 / BK=32
  // bijective XCD swizzle: batch b's 8 m-blocks contiguous -> same XCD
  const int swz = (blockIdx.x & 7) * 64 + (blockIdx.x >> 3);
  const int b  = swz >> 3;
  const int mt = swz & 7;  // 8 m-tiles of 64 rows

  __shared__ __align__(16) char lds[139264];  // A: 2x4KB @0; B: 2x64KB @8192

  const int t = threadIdx.x;
  const int lane = t & 63;
  const int w = t >> 6;  // 8 waves; wave w covers n-slice [w*64, w*64+64) per half

  const u16* gW = Wm + ((size_t)b * L_ + mt * 64) * L_;
  const float* gX = X + (size_t)b * L_ * H_;

  // ---- A staging (threads t<256): row=t>>2 (0..63), 16B slot=t&3, r5 swizzle
  const int arow = t >> 2;
  const int axsw = (arow & 3) ^ ((arow >> 2) & 3);
  const u16* pA0 = gW + (size_t)arow * L_ + ((t & 3) ^ axsw) * 8;
  // dest base (wave-uniform): aslot*4096 + w*1024 (waves 0..3 only)

  // ---- B staging: wave w issues 8 gloads per half: k = 4*i + (w>>1), chunk=w&1
  const int bk_ = w >> 1;   // k mod 4
  const int bch = w & 1;    // which 1KB chunk of the 2KB k-row

  // ---- A fragment read offsets (verbatim r5 pattern, conflict-free)
  int offA[4];
#pragma unroll
  for (int mf = 0; mf < 4; ++mf) {
    int r = mf * 16 + (lane & 15);
    offA[mf] = r * 64 + ((((lane >> 4) ^ (r & 3) ^ ((r >> 2) & 3))) << 4);
  }
  // ---- B gather column offsets (within a 64KB B slot), per nf
  const int o = lane >> 4;  // k-octet
  int offB[4];
#pragma unroll
  for (int nf = 0; nf < 4; ++nf) {
    int n = w * 64 + nf * 16 + (lane & 15);  // n within 512-half
    int ch = n >> 8, g = (n >> 2) & 63;
    offB[nf] = o * 16384 + ch * 1024 + ((g ^ (o << 2)) << 4) + ((n & 3) << 2);
  }

  f32x4 acc[4][8] = {};

#define A_ISSUE(kt)                                                         \
  do {                                                                      \
    if (t < 256) GLOAD(pA0 + (kt) * 32, lds + ((kt) & 1) * 4096 + w * 1024); \
  } while (0)

  // stage half h of K-tile kt into B slot h (8192 + h*65536)
#define BH_ISSUE(kt, h)                                                     \
  do {                                                                      \
    _Pragma("unroll")                                                       \
    for (int i = 0; i < 8; ++i) {                                           \
      int kk = 4 * i + bk_;                                                 \
      GLOAD(gX + (size_t)((kt) * 32 + kk) * H_ + (h) * 512 + bch * 256 +    \
                ((lane ^ ((i >> 1) << 2)) << 2),                            \
            lds + 8192 + (h) * 65536 + kk * 2048 + bch * 1024);             \
    }                                                                       \
  } while (0)

  // build 4 B-frags + 16 MFMA for one half
#define HALF_COMPUTE(kslot, h)                                              \
  do {                                                                      \
    const char* bb = lds + 8192 + (h) * 65536;                              \
    _Pragma("unroll")                                                       \
    for (int nf = 0; nf < 4; ++nf) {                                        \
      union { u16 u[8]; s16x8 v; } pk;                                      \
      _Pragma("unroll")                                                     \
      for (int j = 0; j < 8; ++j)                                           \
        pk.u[j] = f2bf(*(const float*)(bb + offB[nf] + j * 2048));          \
      _Pragma("unroll")                                                     \
      for (int mf = 0; mf < 4; ++mf)                                        \
        acc[mf][(h) * 4 + nf] =                                             \
            __builtin_amdgcn_mfma_f32_16x16x32_bf16(af[mf], pk.v,           \
                                                    acc[mf][(h) * 4 + nf], 0, 0, 0); \
    }                                                                       \
  } while (0)

  // prologue: A(0) -> slot0, B(0,half0) -> B slot0
  A_ISSUE(0); BH_ISSUE(0, 0);
  asm volatile("s_waitcnt vmcnt(0)" ::: "memory");
  __builtin_amdgcn_s_barrier();

#pragma unroll
  for (int k = 0; k < NT; ++k) {
    BH_ISSUE(k, 1);  // half1 of this tile -> B slot1 (nobody reads slot1 now)

    // A frags for this K-tile (retained across both halves)
    const char* ab = lds + (k & 1) * 4096;
    s16x8 af[4];
#pragma unroll
    for (int mf = 0; mf < 4; ++mf) af[mf] = *(const s16x8*)(ab + offA[mf]);

    __builtin_amdgcn_s_setprio(1);
    HALF_COMPUTE(k & 1, 0);
    __builtin_amdgcn_s_setprio(0);

    asm volatile("s_waitcnt vmcnt(0)" ::: "memory");  // half1 landed (issued ~1 phase ago)
    __builtin_amdgcn_s_barrier();                     // slot0 free for rewrite

    if (k + 1 < NT) { A_ISSUE(k + 1); BH_ISSUE(k + 1, 0); }  // next tile -> A slot, B slot0

    __builtin_amdgcn_s_setprio(1);
    HALF_COMPUTE(k & 1, 1);
    __builtin_amdgcn_s_setprio(0);

    if (k + 1 < NT) {
      asm volatile("s_waitcnt vmcnt(0)" ::: "memory");  // next tile landed
      __builtin_amdgcn_s_barrier();                     // slot1 free for rewrite
    }
  }
#undef A_ISSUE
#undef BH_ISSUE
#undef HALF_COMPUTE

  // epilogue: C/D layout col=lane&15, row=(lane>>4)*4+reg  [verified m89/m91]
  const int orow0 = mt * 64 + ((lane >> 4) << 2);
  const int ocol0 = w * 64 + (lane & 15);  // + h*512 via nf index
#pragma unroll
  for (int mf = 0; mf < 4; ++mf)
#pragma unroll
    for (int hh = 0; hh < 2; ++hh)
#pragma unroll
      for (int nf = 0; nf < 4; ++nf)
#pragma unroll
        for (int j = 0; j < 4; ++j) {
          int row = orow0 + mf * 16 + j;
          int col = hh * 512 + ocol0 + nf * 16;
          out[((size_t)b * L_ + row) * H_ + col] = acc[mf][hh * 4 + nf][j];
        }
}

extern "C" void kernel_launch(void* const* d_in, const int* in_sizes, int n_in,
                              void* d_out, int out_size, void* d_ws, size_t ws_size,
                              hipStream_t stream) {
  (void)in_sizes; (void)n_in; (void)out_size; (void)ws_size;
  const float* sent = (const float*)d_in[0];  // [B, L, H] f32
  const float* mask = (const float*)d_in[1];  // [B, L]    f32
  const float* att  = (const float*)d_in[2];  // [B, L, L] f32
  u16* Wm = (u16*)d_ws;                       // [B, L, L] bf16 (32 MiB)
  float* outp = (float*)d_out;                // [B, L, H] f32

  softmax_rows<<<2048, 256, 0, stream>>>(att, mask, Wm);
  gemm_fc<<<B_ * 8, 512, 0, stream>>>(Wm, sent, outp);
}

// Round 15
// 93.816 us; speedup vs baseline: 2.9325x; 2.9325x over previous
//
#include <hip/hip_runtime.h>
#include <hip/hip_bf16.h>

#define B_ 64
#define L_ 512
#define H_ 1024
#define EPS_ 1e-13f

typedef unsigned short u16;
typedef __attribute__((ext_vector_type(8))) short s16x8;
typedef __attribute__((ext_vector_type(4))) float f32x4;

__device__ __forceinline__ u16 f2bf(float f) {
  __hip_bfloat16 h = __float2bfloat16(f);
  union { __hip_bfloat16 h; u16 u; } c; c.h = h; return c.u;
}

// ---- Kernel 1: row softmax + mask renorm -> W bf16 (1x work, BW-bound). ----
__global__ __launch_bounds__(256) void softmax_rows(const float* __restrict__ att,
                                                    const float* __restrict__ mask,
                                                    u16* __restrict__ Wout) {
  const int w = threadIdx.x >> 6, lane = threadIdx.x & 63;
  const int row0 = blockIdx.x * 16 + w * 4;

  float a[4][8];
#pragma unroll
  for (int r = 0; r < 4; ++r) {
    const float* p = att + (size_t)(row0 + r) * L_ + lane * 8;
    float4 v0 = *(const float4*)p;
    float4 v1 = *(const float4*)(p + 4);
    a[r][0] = v0.x; a[r][1] = v0.y; a[r][2] = v0.z; a[r][3] = v0.w;
    a[r][4] = v1.x; a[r][5] = v1.y; a[r][6] = v1.z; a[r][7] = v1.w;
  }

  float m[4];
#pragma unroll
  for (int r = 0; r < 4; ++r) {
    m[r] = a[r][0];
#pragma unroll
    for (int j = 1; j < 8; ++j) m[r] = fmaxf(m[r], a[r][j]);
  }
#pragma unroll
  for (int off = 32; off > 0; off >>= 1)
#pragma unroll
    for (int r = 0; r < 4; ++r) m[r] = fmaxf(m[r], __shfl_xor(m[r], off));

  float z[4] = {0.f, 0.f, 0.f, 0.f};
#pragma unroll
  for (int r = 0; r < 4; ++r)
#pragma unroll
    for (int j = 0; j < 8; ++j) { a[r][j] = __expf(a[r][j] - m[r]); z[r] += a[r][j]; }
#pragma unroll
  for (int off = 32; off > 0; off >>= 1)
#pragma unroll
    for (int r = 0; r < 4; ++r) z[r] += __shfl_xor(z[r], off);

#pragma unroll
  for (int r = 0; r < 4; ++r) {
    const float mk = mask[row0 + r];
    const float c = (1.0f / z[r]) * (mk / (mk + EPS_));  // softmax row-sum == 1
    union { u16 u[8]; uint4 v; } wv;
#pragma unroll
    for (int j = 0; j < 8; ++j) wv.u[j] = f2bf(a[r][j] * c);
    *(uint4*)(Wout + (size_t)(row0 + r) * L_ + lane * 8) = wv.v;
  }
}

#define GLOAD(gp, lp)                                                              \
  __builtin_amdgcn_global_load_lds((const __attribute__((address_space(1))) unsigned*)(gp), \
                                   (__attribute__((address_space(3))) unsigned*)(void*)(lp), 16, 0, 0)

// ---- Kernel 2: GEMM out = W @ X (measured-best r11 variant, 93.7 us total).
// 256x256 tile, 8 waves. A: swizzled gload_lds ring-3 x16KB. B: X tile staged
// row-major f32 via gload_lds (contiguous 1KB k-rows), ring-3 x32KB; transpose
// at LDS-read time via b32 column gather (2-way banks via odd-octet source
// granule^4 pre-swizzle) + cvt bf16. 144KB LDS, depth-2 prefetch, counted
// vmcnt(6), setprio around MFMA, bijective XCD swizzle.
__global__ __launch_bounds__(512, 2) void gemm_xd(const u16* __restrict__ Wm,
                                                  const float* __restrict__ X,
                                                  float* __restrict__ out) {
  const int NT = 16;  // K=512 / BK=32
  const int swz = (blockIdx.x & 7) * 64 + (blockIdx.x >> 3);
  const int b  = swz >> 3;
  const int mt = (swz >> 2) & 1;  // M=512 -> 2 tiles of 256
  const int nt = swz & 3;         // N=1024 -> 4 tiles of 256

  __shared__ __align__(16) char lds[147456];  // A: 3x16KB @0; B(f32): 3x32KB @49152

  const int t = threadIdx.x;
  const int lane = t & 63;
  const int w = t >> 6;               // 8 waves
  const int wm = w >> 2, wn = w & 3;  // 2x4 wave grid, 128x64 out each

  const u16* gW = Wm + ((size_t)b * L_ + mt * 256) * L_;  // L3-hot (33 MB)
  const float* gX = X + (size_t)b * L_ * H_ + nt * 256;

  // ---- A staging: rows r0 / r0+128, 16B slot t&3, XOR swizzle ----
  const int r0 = t >> 2;
  const int xsw = (r0 & 3) ^ ((r0 >> 2) & 3);
  const int scol = ((t & 3) ^ xsw) * 8;
  const u16* pA0 = gW + (size_t)r0 * L_ + scol;
  char* dA = lds + w * 1024;  // + rgn*16384 (+8192 for rows 128..255)

  // ---- B staging: pass p (p=0..3) = k-octet p; wave w stages k-row p*8+w.
  const float* pXw = gX + (size_t)w * H_;
  const int l4  = lane * 4;         // f32 offset of lane's 16B granule
  const int lx4 = (lane ^ 4) * 4;   // pre-swizzled granule for odd octets
  char* dBw = lds + 49152 + w * 1024;  // + rgn*32768 + p*8192

  int offA[8];
#pragma unroll
  for (int mf = 0; mf < 8; ++mf) {
    int r = wm * 128 + mf * 16 + (lane & 15);
    offA[mf] = r * 64 + ((((lane >> 4) ^ (r & 3) ^ ((r >> 2) & 3))) << 4);
  }
  // B column-gather byte offsets: row = oct*8+j, col n at elem (n ^ ((oct&1)<<4))
  int offBc[4];
#pragma unroll
  for (int nf = 0; nf < 4; ++nf) {
    int n = wn * 64 + nf * 16 + (lane & 15);
    int oct = lane >> 4;
    offBc[nf] = oct * 8192 + ((n ^ ((oct & 1) << 4)) << 2);
  }

  f32x4 acc[8][4] = {};

#define A_ISSUE(tt)                                                        \
  do {                                                                     \
    GLOAD(pA0 + (tt) * 32, dA + ((tt) % 3) * 16384);                       \
    GLOAD(pA0 + (tt) * 32 + 128 * (size_t)L_, dA + ((tt) % 3) * 16384 + 8192); \
  } while (0)

#define B_ISSUE(tt)                                                        \
  do {                                                                     \
    GLOAD(pXw + (size_t)((tt) * 32 + 0)  * H_ + l4,  dBw + ((tt) % 3) * 32768);         \
    GLOAD(pXw + (size_t)((tt) * 32 + 8)  * H_ + lx4, dBw + ((tt) % 3) * 32768 + 8192);  \
    GLOAD(pXw + (size_t)((tt) * 32 + 16) * H_ + l4,  dBw + ((tt) % 3) * 32768 + 16384); \
    GLOAD(pXw + (size_t)((tt) * 32 + 24) * H_ + lx4, dBw + ((tt) % 3) * 32768 + 24576); \
  } while (0)

  // prologue: tiles 0,1 in flight (6 vmem each)
  A_ISSUE(0); B_ISSUE(0); A_ISSUE(1); B_ISSUE(1);
  asm volatile("s_waitcnt vmcnt(6)" ::: "memory");  // tile 0 resident
  __builtin_amdgcn_s_barrier();

#pragma unroll
  for (int k = 0; k < NT; ++k) {
    if (k + 2 < NT) { A_ISSUE(k + 2); B_ISSUE(k + 2); }

    const char* baseA = lds + (k % 3) * 16384;
    const char* baseB = lds + 49152 + (k % 3) * 32768;

    s16x8 af[8];
#pragma unroll
    for (int mf = 0; mf < 8; ++mf) af[mf] = *(const s16x8*)(baseA + offA[mf]);

    s16x8 bf4[4];
#pragma unroll
    for (int nf = 0; nf < 4; ++nf) {
      union { u16 u[8]; s16x8 v; } pk;
#pragma unroll
      for (int j = 0; j < 8; ++j)
        pk.u[j] = f2bf(*(const float*)(baseB + offBc[nf] + j * 1024));
      bf4[nf] = pk.v;
    }
    asm volatile("s_waitcnt lgkmcnt(0)" ::: "memory");

    __builtin_amdgcn_s_setprio(1);
#pragma unroll
    for (int mf = 0; mf < 8; ++mf)
#pragma unroll
      for (int nf = 0; nf < 4; ++nf)
        acc[mf][nf] = __builtin_amdgcn_mfma_f32_16x16x32_bf16(af[mf], bf4[nf], acc[mf][nf], 0, 0, 0);
    __builtin_amdgcn_s_setprio(0);

    if (k + 1 < NT) {
      if (k + 2 < NT) asm volatile("s_waitcnt vmcnt(6)" ::: "memory");
      else            asm volatile("s_waitcnt vmcnt(0)" ::: "memory");
      __builtin_amdgcn_s_barrier();
    }
  }
#undef A_ISSUE
#undef B_ISSUE

  // epilogue: C/D layout col=lane&15, row=(lane>>4)*4+reg  [verified m89/m91]
  const int orow0 = mt * 256 + wm * 128 + ((lane >> 4) << 2);
  const int ocol0 = nt * 256 + wn * 64 + (lane & 15);
#pragma unroll
  for (int mf = 0; mf < 8; ++mf)
#pragma unroll
    for (int nf = 0; nf < 4; ++nf)
#pragma unroll
      for (int j = 0; j < 4; ++j) {
        int row = orow0 + mf * 16 + j;
        int col = ocol0 + nf * 16;
        out[((size_t)b * L_ + row) * H_ + col] = acc[mf][nf][j];
      }
}

extern "C" void kernel_launch(void* const* d_in, const int* in_sizes, int n_in,
                              void* d_out, int out_size, void* d_ws, size_t ws_size,
                              hipStream_t stream) {
  (void)in_sizes; (void)n_in; (void)out_size; (void)ws_size;
  const float* sent = (const float*)d_in[0];  // [B, L, H] f32
  const float* mask = (const float*)d_in[1];  // [B, L]    f32
  const float* att  = (const float*)d_in[2];  // [B, L, L] f32
  u16* Wm = (u16*)d_ws;                       // [B, L, L] bf16 (32 MiB)
  float* outp = (float*)d_out;                // [B, L, H] f32

  softmax_rows<<<2048, 256, 0, stream>>>(att, mask, Wm);
  gemm_xd<<<B_ * 2 * 4, 512, 0, stream>>>(Wm, sent, outp);
}